// Round 11
// baseline (252.567 us; speedup 1.0000x reference)
//
#include <hip/hip_runtime.h>
#include <math.h>

// Problem constants (SHAPES fixed; EMB=HID=256, H=8, L=4, P=4)
#define NB    2
#define NQ    11253          // I == N == 92^2+46^2+23^2+12^2
#define NEMB  256
#define NHID  256
#define NH    8
#define NCP   32             // HID / H
#define MROWS (NB * NQ)      // 22506
#define NGRP  (NB * NQ * NH) // 180048

// Level geometry; starts: 0, 8464, 10580, 11109
__device__ __constant__ int LVL_H[4]     = {92, 46, 23, 12};
__device__ __constant__ int LVL_W[4]     = {92, 46, 23, 12};
__device__ __constant__ int LVL_START[4] = {0, 8464, 10580, 11109};

typedef float  f32x4  __attribute__((ext_vector_type(4)));
typedef __bf16 bf16x8 __attribute__((ext_vector_type(8)));
typedef __bf16 bf16x4v __attribute__((ext_vector_type(4)));
typedef short  s16x8  __attribute__((ext_vector_type(8)));  // MFMA operand view

// ---------------------------------------------------------------------------
// fp32 -> (hi, lo) bf16 planes; n = nch*8 elements, nch chunks of 8.
// ---------------------------------------------------------------------------
__global__ __launch_bounds__(256) void convert_hilo(
    const float* __restrict__ src, __bf16* __restrict__ hi,
    __bf16* __restrict__ lo, int nch)
{
    int i = blockIdx.x * 256 + threadIdx.x;
    const int stride = gridDim.x * 256;
    for (; i < nch; i += stride) {
        const float* p = src + (size_t)i * 8;
        float4 a = *(const float4*)p;
        float4 b = *(const float4*)(p + 4);
        float v[8] = {a.x, a.y, a.z, a.w, b.x, b.y, b.z, b.w};
        bf16x8 h, l;
        #pragma unroll
        for (int j = 0; j < 8; ++j) {
            __bf16 hh = (__bf16)v[j];
            h[j] = hh; l[j] = (__bf16)(v[j] - (float)hh);
        }
        *(bf16x8*)(hi + (size_t)i * 8) = h;
        *(bf16x8*)(lo + (size_t)i * 8) = l;
    }
}

// ---------------------------------------------------------------------------
// Weights: W [K=256][N] fp32 -> W^T hi/lo bf16 [N][256].
// Sections: W_img (N=256, 8192 chunks), W_q (N=384, 12288), W_out (N=256, 8192).
// idx = k8*N + n within a section -> consecutive lanes read consecutive n
// (coalesced); 16B transposed stores (small matrix, L2 absorbs).
// ---------------------------------------------------------------------------
__global__ __launch_bounds__(256) void convert_w_T(
    const float* __restrict__ W_img, const float* __restrict__ W_q,
    const float* __restrict__ W_out,
    __bf16* __restrict__ WiTh, __bf16* __restrict__ WiTl,
    __bf16* __restrict__ WqTh, __bf16* __restrict__ WqTl,
    __bf16* __restrict__ WoTh, __bf16* __restrict__ WoTl)
{
    int idx = blockIdx.x * 256 + threadIdx.x;     // 0 .. 28671
    const float* W; __bf16 *Th, *Tl; int Nn, r;
    if (idx < 8192)       { W = W_img; Th = WiTh; Tl = WiTl; Nn = 256; r = idx; }
    else if (idx < 20480) { W = W_q;   Th = WqTh; Tl = WqTl; Nn = 384; r = idx - 8192; }
    else                  { W = W_out; Th = WoTh; Tl = WoTl; Nn = 256; r = idx - 20480; }
    const int n  = r % Nn;
    const int k0 = (r / Nn) * 8;
    bf16x8 h, l;
    #pragma unroll
    for (int j = 0; j < 8; ++j) {
        float v = W[(size_t)(k0 + j) * Nn + n];
        __bf16 hh = (__bf16)v;
        h[j] = hh; l[j] = (__bf16)(v - (float)hh);
    }
    *(bf16x8*)(Th + (size_t)n * 256 + k0) = h;
    *(bf16x8*)(Tl + (size_t)n * 256 + k0) = l;
}

// ---------------------------------------------------------------------------
// bf16-split MFMA GEMM: C[M,N] = A@B + bias, fp32 out.
// 3-term split: hh + hl + lh (rel err ~2^-16). B given pre-converted+transposed
// (BhT/BlT bf16 [N][K]). A either fp32 (PREA=false, in-loop split) or
// pre-converted planes (PREA=true).
// Tile 128x128x32; 4 waves (2x2 of 64x64); 4x4 frags of mfma_f32_16x16x32_bf16.
// Fragment maps (m89/m91): A: row=lane&15, k=(lane>>4)*8+i; B: col=lane&15,
// same k; D: col=lane&15, row=(lane>>4)*4+reg. LDS k-stride 40 (80B).
// ---------------------------------------------------------------------------
#define BM 128
#define BN 128
#define BK 32
#define LDK 40

template<bool PREA>
__global__ __launch_bounds__(256) void gemm_mfma(
    const float* __restrict__ A32,
    const __bf16* __restrict__ Ah_g, const __bf16* __restrict__ Al_g,
    const __bf16* __restrict__ BhT, const __bf16* __restrict__ BlT,
    const float* __restrict__ bias, float* __restrict__ C,
    int M, int N, int K)
{
    __shared__ __bf16 Ah[BM * LDK];
    __shared__ __bf16 Al[BM * LDK];
    __shared__ __bf16 Bh[BN * LDK];
    __shared__ __bf16 Bl[BN * LDK];

    const int t    = threadIdx.x;
    const int brow = blockIdx.x * BM;
    const int bcol = blockIdx.y * BN;
    const int wave = t >> 6;
    const int lane = t & 63;
    const int wr   = (wave >> 1) * 64;
    const int wc   = (wave & 1) * 64;
    const int l15  = lane & 15;
    const int l4   = lane >> 4;

    f32x4 acc[4][4] = {};

    // A staging: thread t covers row (t>>1), k = (t&1)*16 .. +15
    const int ar = t >> 1;
    const int ak = (t & 1) * 16;
    const int grow = brow + ar;
    // B staging: thread t covers col (t>>1), same 16-k half
    const int bcr = t >> 1;

    for (int k0 = 0; k0 < K; k0 += BK) {
        // ---- stage A
        if constexpr (PREA) {
            s16x8 h0 = {}, h1 = {}, l0 = {}, l1 = {};
            if (grow < M) {
                const __bf16* hp = Ah_g + (size_t)grow * K + k0 + ak;
                const __bf16* lp = Al_g + (size_t)grow * K + k0 + ak;
                h0 = *(const s16x8*)hp;  h1 = *(const s16x8*)(hp + 8);
                l0 = *(const s16x8*)lp;  l1 = *(const s16x8*)(lp + 8);
            }
            *(s16x8*)&Ah[ar * LDK + ak]     = h0;
            *(s16x8*)&Ah[ar * LDK + ak + 8] = h1;
            *(s16x8*)&Al[ar * LDK + ak]     = l0;
            *(s16x8*)&Al[ar * LDK + ak + 8] = l1;
        } else {
            float va[16];
            if (grow < M) {
                const float* ap = A32 + (size_t)grow * K + k0 + ak;
                *(float4*)&va[0]  = *(const float4*)(ap + 0);
                *(float4*)&va[4]  = *(const float4*)(ap + 4);
                *(float4*)&va[8]  = *(const float4*)(ap + 8);
                *(float4*)&va[12] = *(const float4*)(ap + 12);
            } else {
                #pragma unroll
                for (int i = 0; i < 16; ++i) va[i] = 0.f;
            }
            bf16x8 h0, h1, l0, l1;
            #pragma unroll
            for (int i = 0; i < 8; ++i) {
                __bf16 h = (__bf16)va[i];
                h0[i] = h;  l0[i] = (__bf16)(va[i] - (float)h);
            }
            #pragma unroll
            for (int i = 0; i < 8; ++i) {
                __bf16 h = (__bf16)va[8 + i];
                h1[i] = h;  l1[i] = (__bf16)(va[8 + i] - (float)h);
            }
            *(bf16x8*)&Ah[ar * LDK + ak]     = h0;
            *(bf16x8*)&Ah[ar * LDK + ak + 8] = h1;
            *(bf16x8*)&Al[ar * LDK + ak]     = l0;
            *(bf16x8*)&Al[ar * LDK + ak + 8] = l1;
        }
        // ---- stage B (pre-converted, transposed: pure 16B copies)
        {
            const __bf16* bp = BhT + (size_t)(bcol + bcr) * K + k0 + ak;
            const __bf16* lp = BlT + (size_t)(bcol + bcr) * K + k0 + ak;
            s16x8 h0 = *(const s16x8*)bp, h1 = *(const s16x8*)(bp + 8);
            s16x8 l0 = *(const s16x8*)lp, l1 = *(const s16x8*)(lp + 8);
            *(s16x8*)&Bh[bcr * LDK + ak]     = h0;
            *(s16x8*)&Bh[bcr * LDK + ak + 8] = h1;
            *(s16x8*)&Bl[bcr * LDK + ak]     = l0;
            *(s16x8*)&Bl[bcr * LDK + ak + 8] = l1;
        }
        __syncthreads();

        // ---- fragments + MFMA
        s16x8 a_h[4], a_l[4], b_h[4], b_l[4];
        #pragma unroll
        for (int mi = 0; mi < 4; ++mi) {
            int off = (wr + mi * 16 + l15) * LDK + l4 * 8;
            a_h[mi] = *(s16x8*)&Ah[off];
            a_l[mi] = *(s16x8*)&Al[off];
        }
        #pragma unroll
        for (int ni = 0; ni < 4; ++ni) {
            int off = (wc + ni * 16 + l15) * LDK + l4 * 8;
            b_h[ni] = *(s16x8*)&Bh[off];
            b_l[ni] = *(s16x8*)&Bl[off];
        }
        #pragma unroll
        for (int mi = 0; mi < 4; ++mi)
            #pragma unroll
            for (int ni = 0; ni < 4; ++ni) {
                acc[mi][ni] = __builtin_amdgcn_mfma_f32_16x16x32_bf16(a_h[mi], b_h[ni], acc[mi][ni], 0, 0, 0);
                acc[mi][ni] = __builtin_amdgcn_mfma_f32_16x16x32_bf16(a_h[mi], b_l[ni], acc[mi][ni], 0, 0, 0);
                acc[mi][ni] = __builtin_amdgcn_mfma_f32_16x16x32_bf16(a_l[mi], b_h[ni], acc[mi][ni], 0, 0, 0);
            }
        __syncthreads();
    }

    // ---- epilogue: D mapping col=lane&15, row=(lane>>4)*4+reg
    #pragma unroll
    for (int ni = 0; ni < 4; ++ni) {
        const int col = bcol + wc + ni * 16 + l15;
        const float bv = bias[col];
        #pragma unroll
        for (int mi = 0; mi < 4; ++mi) {
            #pragma unroll
            for (int j = 0; j < 4; ++j) {
                int row = brow + wr + mi * 16 + l4 * 4 + j;
                if (row < M) C[(size_t)row * N + col] = acc[mi][ni][j] + bv;
            }
        }
    }
}

// ---------------------------------------------------------------------------
// Fused MSDA, 8 lanes per (b,n,h), lane = 4 channels (float4 gathers).
// Output emitted directly as hi/lo bf16 planes (A-input of GEMM3).
// ---------------------------------------------------------------------------
__global__ __launch_bounds__(256) void msda_kernel(
    const float* __restrict__ img_p, const float* __restrict__ qp,
    const float* __restrict__ refp,
    __bf16* __restrict__ outH, __bf16* __restrict__ outL)
{
    __shared__ int smem[16][32][8];   // 16 KB
    const int t  = threadIdx.x;
    const int t3 = t & 7;
    const int g  = t >> 3;                 // group slot in block (0..31)
    int gid = blockIdx.x * 32 + g;         // (b*NQ+n)*NH + h
    const bool valid = gid < NGRP;
    if (!valid) gid = NGRP - 1;            // clamp: keep all lanes live for barrier
    const int h  = gid & 7;
    const int bn = gid >> 3;
    const int b  = (bn >= NQ) ? 1 : 0;

    const float* q  = qp + (size_t)bn * 384 + h * 48;
    const float rx = refp[bn * 2 + 0];
    const float ry = refp[bn * 2 + 1];

    // producer: own samples s0=t3, s1=t3+8; softmax via shfl_xor width 8
    const float ox0 = q[t3 * 3 + 0],        oy0 = q[t3 * 3 + 1],        sc0 = q[t3 * 3 + 2];
    const float ox1 = q[(t3 + 8) * 3 + 0],  oy1 = q[(t3 + 8) * 3 + 1],  sc1 = q[(t3 + 8) * 3 + 2];

    float mx = fmaxf(sc0, sc1);
    mx = fmaxf(mx, __shfl_xor(mx, 1, 8));
    mx = fmaxf(mx, __shfl_xor(mx, 2, 8));
    mx = fmaxf(mx, __shfl_xor(mx, 4, 8));
    const float e0 = __expf(sc0 - mx);
    const float e1 = __expf(sc1 - mx);
    float sum = e0 + e1;
    sum += __shfl_xor(sum, 1, 8);
    sum += __shfl_xor(sum, 2, 8);
    sum += __shfl_xor(sum, 4, 8);
    const float inv = 1.0f / sum;

    #pragma unroll
    for (int which = 0; which < 2; ++which) {
        const int   s  = which ? (t3 + 8) : t3;
        const float ox = which ? ox1 : ox0;
        const float oy = which ? oy1 : oy0;
        const float aw = (which ? e1 : e0) * inv;
        const int l  = s >> 2;
        const int hh = LVL_H[l], ww = LVL_W[l], st = LVL_START[l];
        float x = (rx + ox) * (float)(ww - 1);
        float y = (ry + oy) * (float)(hh - 1);
        x = fminf(fmaxf(x, 0.f), (float)(ww - 1));
        y = fminf(fmaxf(y, 0.f), (float)(hh - 1));
        const float x0f = floorf(x), y0f = floorf(y);
        const int   x0 = (int)x0f,  y0 = (int)y0f;
        const float wx = x - x0f,   wy = y - y0f;
        const int dxb = (x0 < ww - 1) ? (NH * NCP * 4) : 0;        // +1 col, bytes
        const int dyb = (y0 < hh - 1) ? (ww * NH * NCP * 4) : 0;   // +1 row, bytes
        const int o00 = (st + y0 * ww + x0) * (NH * NCP * 4);      // pixel byte offset
        const float u0 = aw * (1.f - wx), u1 = aw * wx;
        int4 pa = make_int4(o00, dxb, dyb, __float_as_int(u0 * (1.f - wy)));
        int4 pb = make_int4(__float_as_int(u1 * (1.f - wy)),
                            __float_as_int(u0 * wy),
                            __float_as_int(u1 * wy), 0);
        *(int4*)&smem[s][g][0] = pa;
        *(int4*)&smem[s][g][4] = pb;
    }
    __syncthreads();

    // consumer: lane covers channels cp = t3*4 .. +3
    const char* base = (const char*)img_p
        + (((size_t)b * NQ * (NH * NCP) + h * NCP + t3 * 4) * 4);
    f32x4 acc = {0.f, 0.f, 0.f, 0.f};
    #pragma unroll
    for (int s = 0; s < 16; ++s) {
        const int4 pa = *(int4*)&smem[s][g][0];
        const int4 pb = *(int4*)&smem[s][g][4];
        const int o00 = pa.x;
        const int o01 = o00 + pa.y;
        const int o10 = o00 + pa.z;
        const int o11 = o10 + pa.y;
        const f32x4 v00 = *(const f32x4*)(base + o00);
        const f32x4 v01 = *(const f32x4*)(base + o01);
        const f32x4 v10 = *(const f32x4*)(base + o10);
        const f32x4 v11 = *(const f32x4*)(base + o11);
        acc += v00 * __int_as_float(pa.w);
        acc += v01 * __int_as_float(pb.x);
        acc += v10 * __int_as_float(pb.y);
        acc += v11 * __int_as_float(pb.z);
    }
    if (valid) {
        bf16x4v hv, lv;
        #pragma unroll
        for (int j = 0; j < 4; ++j) {
            __bf16 hh = (__bf16)acc[j];
            hv[j] = hh; lv[j] = (__bf16)(acc[j] - (float)hh);
        }
        const size_t o = (size_t)bn * NHID + h * NCP + t3 * 4;
        *(bf16x4v*)(outH + o) = hv;
        *(bf16x4v*)(outL + o) = lv;
    }
}

// ---------------------------------------------------------------------------
extern "C" void kernel_launch(void* const* d_in, const int* in_sizes, int n_in,
                              void* d_out, int out_size, void* d_ws, size_t ws_size,
                              hipStream_t stream) {
    const float* img     = (const float*)d_in[0];
    // d_in[1] = shapes (int32) -- hardcoded
    const float* queries = (const float*)d_in[2];
    const float* refp    = (const float*)d_in[3];
    const float* W_img   = (const float*)d_in[4];
    const float* b_img   = (const float*)d_in[5];
    const float* W_q     = (const float*)d_in[6];
    const float* b_q     = (const float*)d_in[7];
    const float* W_out   = (const float*)d_in[8];
    const float* b_out   = (const float*)d_in[9];
    float* out = (float*)d_out;

    // workspace layout
    const size_t NA = (size_t)MROWS * 256;   // 5,761,536 (img / img_p / msda planes)
    float*  img_p = (float*)d_ws;                       // NA f32
    float*  qp    = img_p + NA;                         // MROWS*384 f32
    __bf16* msdaH = (__bf16*)(qp + (size_t)MROWS * 384);
    __bf16* msdaL = msdaH + NA;
    __bf16* WiTh  = msdaL + NA;
    __bf16* WiTl  = WiTh + 256 * 256;
    __bf16* WqTh  = WiTl + 256 * 256;
    __bf16* WqTl  = WqTh + 384 * 256;
    __bf16* WoTh  = WqTl + 384 * 256;
    __bf16* WoTl  = WoTh + 256 * 256;
    __bf16* baseEnd = WoTl + 256 * 256;
    // optional A-side pre-converted planes (img, queries)
    __bf16* imgH = baseEnd;
    __bf16* imgL = imgH + NA;
    __bf16* qH   = imgL + NA;
    __bf16* qL   = qH + NA;
    const size_t need_full = (size_t)((char*)(qL + NA) - (char*)d_ws);
    const bool FULL = ws_size >= need_full;   // constant per session -> graph-safe

    const int gRows = (MROWS + BM - 1) / BM;  // 176

    // 0. weights -> W^T hi/lo bf16 (28672 chunks)
    convert_w_T<<<112, 256, 0, stream>>>(W_img, W_q, W_out,
                                         WiTh, WiTl, WqTh, WqTl, WoTh, WoTl);

    if (FULL) {
        // 0b. activations -> hi/lo planes (720192 chunks each)
        convert_hilo<<<2048, 256, 0, stream>>>(img,     imgH, imgL, (int)(NA / 8));
        convert_hilo<<<2048, 256, 0, stream>>>(queries, qH,   qL,   (int)(NA / 8));
        // 1. img_p = img @ W_img + b_img
        gemm_mfma<true><<<dim3(gRows, 2), 256, 0, stream>>>(
            nullptr, imgH, imgL, WiTh, WiTl, b_img, img_p, MROWS, 256, 256);
        // 2. qp = queries @ W_q + b_q
        gemm_mfma<true><<<dim3(gRows, 3), 256, 0, stream>>>(
            nullptr, qH, qL, WqTh, WqTl, b_q, qp, MROWS, 384, 256);
    } else {
        gemm_mfma<false><<<dim3(gRows, 2), 256, 0, stream>>>(
            img, nullptr, nullptr, WiTh, WiTl, b_img, img_p, MROWS, 256, 256);
        gemm_mfma<false><<<dim3(gRows, 3), 256, 0, stream>>>(
            queries, nullptr, nullptr, WqTh, WqTl, b_q, qp, MROWS, 384, 256);
    }

    // 3. fused softmax + sampling + weighted sum -> hi/lo bf16
    msda_kernel<<<(NGRP + 31) / 32, 256, 0, stream>>>(img_p, qp, refp, msdaH, msdaL);

    // 4. out = msda_out @ W_out + b_out
    gemm_mfma<true><<<dim3(gRows, 2), 256, 0, stream>>>(
        nullptr, msdaH, msdaL, WoTh, WoTl, b_out, out, MROWS, 256, 256);
}

// Round 12
// 229.931 us; speedup vs baseline: 1.0984x; 1.0984x over previous
//
#include <hip/hip_runtime.h>
#include <math.h>

// Problem constants (SHAPES fixed; EMB=HID=256, H=8, L=4, P=4)
#define NB    2
#define NQ    11253          // I == N == 92^2+46^2+23^2+12^2
#define NEMB  256
#define NHID  256
#define NH    8
#define NCP   32             // HID / H
#define MROWS (NB * NQ)      // 22506
#define NGRP  (NB * NQ * NH) // 180048

// Level geometry; starts: 0, 8464, 10580, 11109
__device__ __constant__ int LVL_H[4]     = {92, 46, 23, 12};
__device__ __constant__ int LVL_W[4]     = {92, 46, 23, 12};
__device__ __constant__ int LVL_START[4] = {0, 8464, 10580, 11109};

typedef float  f32x4   __attribute__((ext_vector_type(4)));
typedef __bf16 bf16x8  __attribute__((ext_vector_type(8)));
typedef __bf16 bf16x4v __attribute__((ext_vector_type(4)));
typedef short  s16x8   __attribute__((ext_vector_type(8)));  // MFMA operand view

// ---------------------------------------------------------------------------
// Weights: W [K=256][N] fp32 -> W^T hi/lo bf16 [N][256].
// Verified in round 11 (all GEMMs consumed these, passed).
// ---------------------------------------------------------------------------
__global__ __launch_bounds__(256) void convert_w_T(
    const float* __restrict__ W_img, const float* __restrict__ W_q,
    const float* __restrict__ W_out,
    __bf16* __restrict__ WiTh, __bf16* __restrict__ WiTl,
    __bf16* __restrict__ WqTh, __bf16* __restrict__ WqTl,
    __bf16* __restrict__ WoTh, __bf16* __restrict__ WoTl)
{
    int idx = blockIdx.x * 256 + threadIdx.x;     // 0 .. 28671
    const float* W; __bf16 *Th, *Tl; int Nn, r;
    if (idx < 8192)       { W = W_img; Th = WiTh; Tl = WiTl; Nn = 256; r = idx; }
    else if (idx < 20480) { W = W_q;   Th = WqTh; Tl = WqTl; Nn = 384; r = idx - 8192; }
    else                  { W = W_out; Th = WoTh; Tl = WoTl; Nn = 256; r = idx - 20480; }
    const int n  = r % Nn;
    const int k0 = (r / Nn) * 8;
    bf16x8 h, l;
    #pragma unroll
    for (int j = 0; j < 8; ++j) {
        float v = W[(size_t)(k0 + j) * Nn + n];
        __bf16 hh = (__bf16)v;
        h[j] = hh; l[j] = (__bf16)(v - (float)hh);
    }
    *(bf16x8*)(Th + (size_t)n * 256 + k0) = h;
    *(bf16x8*)(Tl + (size_t)n * 256 + k0) = l;
}

// ---------------------------------------------------------------------------
// bf16-split MFMA GEMM, 64x64 tile for grid parallelism (this round's change):
// grid = (M/64) x (N/64) = 1408..2112 blocks -> ~6-8 blocks/CU resident
// (LDS 20.5 KB/block), TLP hides staging latency that dominated the 128x128
// version (352 blocks = 1.4/CU).
// 3-term split hh+hl+lh (rel err ~2^-16). B pre-converted+transposed [N][K].
// A: fp32 in-loop split (PREA=false) or hi/lo planes (PREA=true).
// 4 waves = 2x2 of 32x32; 2x2 frags of v_mfma_f32_16x16x32_bf16.
// Fragment maps (m89/m91, verified on-device rounds 10/11): A row=lane&15,
// k=(lane>>4)*8+i; B col=lane&15 same k; D col=lane&15, row=(lane>>4)*4+reg.
// LDS k-stride 40 (80 B) -> 2-way bank aliasing on b128 frag reads (free, m136).
// ---------------------------------------------------------------------------
#define BM 64
#define BN 64
#define BK 32
#define LDK 40

template<bool PREA>
__global__ __launch_bounds__(256) void gemm64(
    const float* __restrict__ A32,
    const __bf16* __restrict__ AhG, const __bf16* __restrict__ AlG,
    const __bf16* __restrict__ BhT, const __bf16* __restrict__ BlT,
    const float* __restrict__ bias, float* __restrict__ C,
    int M, int N, int K)
{
    __shared__ __bf16 Ah[BM * LDK];
    __shared__ __bf16 Al[BM * LDK];
    __shared__ __bf16 Bh[BN * LDK];
    __shared__ __bf16 Bl[BN * LDK];

    const int t    = threadIdx.x;
    const int brow = blockIdx.x * BM;
    const int bcol = blockIdx.y * BN;
    const int wave = t >> 6;
    const int lane = t & 63;
    const int wr   = (wave >> 1) * 32;
    const int wc   = (wave & 1) * 32;
    const int l15  = lane & 15;
    const int l4   = lane >> 4;

    f32x4 acc[2][2] = {};

    // staging: thread t covers row/col (t>>2), k-chunk (t&3)*8
    const int sr = t >> 2;
    const int sk = (t & 3) * 8;
    const int grow = brow + sr;

    for (int k0 = 0; k0 < K; k0 += BK) {
        // ---- stage A (hi/lo)
        if constexpr (PREA) {
            s16x8 h = {}, l = {};
            if (grow < M) {
                h = *(const s16x8*)(AhG + (size_t)grow * K + k0 + sk);
                l = *(const s16x8*)(AlG + (size_t)grow * K + k0 + sk);
            }
            *(s16x8*)&Ah[sr * LDK + sk] = h;
            *(s16x8*)&Al[sr * LDK + sk] = l;
        } else {
            float va[8];
            if (grow < M) {
                const float* ap = A32 + (size_t)grow * K + k0 + sk;
                *(float4*)&va[0] = *(const float4*)(ap + 0);
                *(float4*)&va[4] = *(const float4*)(ap + 4);
            } else {
                #pragma unroll
                for (int i = 0; i < 8; ++i) va[i] = 0.f;
            }
            bf16x8 h, l;
            #pragma unroll
            for (int i = 0; i < 8; ++i) {
                __bf16 hh = (__bf16)va[i];
                h[i] = hh; l[i] = (__bf16)(va[i] - (float)hh);
            }
            *(bf16x8*)&Ah[sr * LDK + sk] = h;
            *(bf16x8*)&Al[sr * LDK + sk] = l;
        }
        // ---- stage B (pre-converted W^T: pure 16B copies)
        {
            *(s16x8*)&Bh[sr * LDK + sk] =
                *(const s16x8*)(BhT + (size_t)(bcol + sr) * K + k0 + sk);
            *(s16x8*)&Bl[sr * LDK + sk] =
                *(const s16x8*)(BlT + (size_t)(bcol + sr) * K + k0 + sk);
        }
        __syncthreads();

        // ---- fragments + MFMA (12 per iter)
        s16x8 a_h[2], a_l[2], b_h[2], b_l[2];
        #pragma unroll
        for (int mi = 0; mi < 2; ++mi) {
            int off = (wr + mi * 16 + l15) * LDK + l4 * 8;
            a_h[mi] = *(s16x8*)&Ah[off];
            a_l[mi] = *(s16x8*)&Al[off];
        }
        #pragma unroll
        for (int ni = 0; ni < 2; ++ni) {
            int off = (wc + ni * 16 + l15) * LDK + l4 * 8;
            b_h[ni] = *(s16x8*)&Bh[off];
            b_l[ni] = *(s16x8*)&Bl[off];
        }
        #pragma unroll
        for (int mi = 0; mi < 2; ++mi)
            #pragma unroll
            for (int ni = 0; ni < 2; ++ni) {
                acc[mi][ni] = __builtin_amdgcn_mfma_f32_16x16x32_bf16(a_h[mi], b_h[ni], acc[mi][ni], 0, 0, 0);
                acc[mi][ni] = __builtin_amdgcn_mfma_f32_16x16x32_bf16(a_h[mi], b_l[ni], acc[mi][ni], 0, 0, 0);
                acc[mi][ni] = __builtin_amdgcn_mfma_f32_16x16x32_bf16(a_l[mi], b_h[ni], acc[mi][ni], 0, 0, 0);
            }
        __syncthreads();
    }

    // ---- epilogue: D map col=lane&15, row=(lane>>4)*4+reg
    #pragma unroll
    for (int ni = 0; ni < 2; ++ni) {
        const int col = bcol + wc + ni * 16 + l15;
        const float bv = bias[col];
        #pragma unroll
        for (int mi = 0; mi < 2; ++mi) {
            #pragma unroll
            for (int j = 0; j < 4; ++j) {
                int row = brow + wr + mi * 16 + l4 * 4 + j;
                if (row < M) C[(size_t)row * N + col] = acc[mi][ni][j] + bv;
            }
        }
    }
}

// ---------------------------------------------------------------------------
// Fused MSDA (byte-identical to round 10/11 verified version, hi/lo output).
// 8 lanes per (b,n,h), lane = 4 channels (float4 gathers).
// ---------------------------------------------------------------------------
__global__ __launch_bounds__(256) void msda_kernel(
    const float* __restrict__ img_p, const float* __restrict__ qp,
    const float* __restrict__ refp,
    __bf16* __restrict__ outH, __bf16* __restrict__ outL)
{
    __shared__ int smem[16][32][8];   // 16 KB
    const int t  = threadIdx.x;
    const int t3 = t & 7;
    const int g  = t >> 3;                 // group slot in block (0..31)
    int gid = blockIdx.x * 32 + g;         // (b*NQ+n)*NH + h
    const bool valid = gid < NGRP;
    if (!valid) gid = NGRP - 1;            // clamp: keep all lanes live for barrier
    const int h  = gid & 7;
    const int bn = gid >> 3;
    const int b  = (bn >= NQ) ? 1 : 0;

    const float* q  = qp + (size_t)bn * 384 + h * 48;
    const float rx = refp[bn * 2 + 0];
    const float ry = refp[bn * 2 + 1];

    const float ox0 = q[t3 * 3 + 0],        oy0 = q[t3 * 3 + 1],        sc0 = q[t3 * 3 + 2];
    const float ox1 = q[(t3 + 8) * 3 + 0],  oy1 = q[(t3 + 8) * 3 + 1],  sc1 = q[(t3 + 8) * 3 + 2];

    float mx = fmaxf(sc0, sc1);
    mx = fmaxf(mx, __shfl_xor(mx, 1, 8));
    mx = fmaxf(mx, __shfl_xor(mx, 2, 8));
    mx = fmaxf(mx, __shfl_xor(mx, 4, 8));
    const float e0 = __expf(sc0 - mx);
    const float e1 = __expf(sc1 - mx);
    float sum = e0 + e1;
    sum += __shfl_xor(sum, 1, 8);
    sum += __shfl_xor(sum, 2, 8);
    sum += __shfl_xor(sum, 4, 8);
    const float inv = 1.0f / sum;

    #pragma unroll
    for (int which = 0; which < 2; ++which) {
        const int   s  = which ? (t3 + 8) : t3;
        const float ox = which ? ox1 : ox0;
        const float oy = which ? oy1 : oy0;
        const float aw = (which ? e1 : e0) * inv;
        const int l  = s >> 2;
        const int hh = LVL_H[l], ww = LVL_W[l], st = LVL_START[l];
        float x = (rx + ox) * (float)(ww - 1);
        float y = (ry + oy) * (float)(hh - 1);
        x = fminf(fmaxf(x, 0.f), (float)(ww - 1));
        y = fminf(fmaxf(y, 0.f), (float)(hh - 1));
        const float x0f = floorf(x), y0f = floorf(y);
        const int   x0 = (int)x0f,  y0 = (int)y0f;
        const float wx = x - x0f,   wy = y - y0f;
        const int dxb = (x0 < ww - 1) ? (NH * NCP * 4) : 0;        // +1 col, bytes
        const int dyb = (y0 < hh - 1) ? (ww * NH * NCP * 4) : 0;   // +1 row, bytes
        const int o00 = (st + y0 * ww + x0) * (NH * NCP * 4);      // pixel byte offset
        const float u0 = aw * (1.f - wx), u1 = aw * wx;
        int4 pa = make_int4(o00, dxb, dyb, __float_as_int(u0 * (1.f - wy)));
        int4 pb = make_int4(__float_as_int(u1 * (1.f - wy)),
                            __float_as_int(u0 * wy),
                            __float_as_int(u1 * wy), 0);
        *(int4*)&smem[s][g][0] = pa;
        *(int4*)&smem[s][g][4] = pb;
    }
    __syncthreads();

    const char* base = (const char*)img_p
        + (((size_t)b * NQ * (NH * NCP) + h * NCP + t3 * 4) * 4);
    f32x4 acc = {0.f, 0.f, 0.f, 0.f};
    #pragma unroll
    for (int s = 0; s < 16; ++s) {
        const int4 pa = *(int4*)&smem[s][g][0];
        const int4 pb = *(int4*)&smem[s][g][4];
        const int o00 = pa.x;
        const int o01 = o00 + pa.y;
        const int o10 = o00 + pa.z;
        const int o11 = o10 + pa.y;
        const f32x4 v00 = *(const f32x4*)(base + o00);
        const f32x4 v01 = *(const f32x4*)(base + o01);
        const f32x4 v10 = *(const f32x4*)(base + o10);
        const f32x4 v11 = *(const f32x4*)(base + o11);
        acc += v00 * __int_as_float(pa.w);
        acc += v01 * __int_as_float(pb.x);
        acc += v10 * __int_as_float(pb.y);
        acc += v11 * __int_as_float(pb.z);
    }
    if (valid) {
        bf16x4v hv, lv;
        #pragma unroll
        for (int j = 0; j < 4; ++j) {
            __bf16 hh = (__bf16)acc[j];
            hv[j] = hh; lv[j] = (__bf16)(acc[j] - (float)hh);
        }
        const size_t o = (size_t)bn * NHID + h * NCP + t3 * 4;
        *(bf16x4v*)(outH + o) = hv;
        *(bf16x4v*)(outL + o) = lv;
    }
}

// ---------------------------------------------------------------------------
extern "C" void kernel_launch(void* const* d_in, const int* in_sizes, int n_in,
                              void* d_out, int out_size, void* d_ws, size_t ws_size,
                              hipStream_t stream) {
    const float* img     = (const float*)d_in[0];
    // d_in[1] = shapes (int32) -- hardcoded
    const float* queries = (const float*)d_in[2];
    const float* refp    = (const float*)d_in[3];
    const float* W_img   = (const float*)d_in[4];
    const float* b_img   = (const float*)d_in[5];
    const float* W_q     = (const float*)d_in[6];
    const float* b_q     = (const float*)d_in[7];
    const float* W_out   = (const float*)d_in[8];
    const float* b_out   = (const float*)d_in[9];
    float* out = (float*)d_out;

    // workspace (82.4 MB): img_p | qp | msdaH | msdaL | W^T planes
    const size_t NA = (size_t)MROWS * 256;
    float*  img_p = (float*)d_ws;
    float*  qp    = img_p + NA;
    __bf16* msdaH = (__bf16*)(qp + (size_t)MROWS * 384);
    __bf16* msdaL = msdaH + NA;
    __bf16* WiTh  = msdaL + NA;
    __bf16* WiTl  = WiTh + 256 * 256;
    __bf16* WqTh  = WiTl + 256 * 256;
    __bf16* WqTl  = WqTh + 384 * 256;
    __bf16* WoTh  = WqTl + 384 * 256;
    __bf16* WoTl  = WoTh + 256 * 256;

    const int gRows = (MROWS + BM - 1) / BM;   // 352

    // 0. weights -> W^T hi/lo bf16
    convert_w_T<<<112, 256, 0, stream>>>(W_img, W_q, W_out,
                                         WiTh, WiTl, WqTh, WqTl, WoTh, WoTl);
    // 1. img_p = img @ W_img + b_img      (1408 blocks)
    gemm64<false><<<dim3(gRows, 4), 256, 0, stream>>>(
        img, nullptr, nullptr, WiTh, WiTl, b_img, img_p, MROWS, 256, 256);
    // 2. qp = queries @ W_q + b_q         (2112 blocks)
    gemm64<false><<<dim3(gRows, 6), 256, 0, stream>>>(
        queries, nullptr, nullptr, WqTh, WqTl, b_q, qp, MROWS, 384, 256);
    // 3. fused softmax + sampling + weighted sum -> hi/lo bf16
    msda_kernel<<<(NGRP + 31) / 32, 256, 0, stream>>>(img_p, qp, refp, msdaH, msdaL);
    // 4. out = msda_out @ W_out + b_out   (1408 blocks)
    gemm64<true><<<dim3(gRows, 4), 256, 0, stream>>>(
        nullptr, msdaH, msdaL, WoTh, WoTl, b_out, out, MROWS, 256, 256);
}